// Round 2
// baseline (557.848 us; speedup 1.0000x reference)
//
#include <hip/hip_runtime.h>
#include <cstdint>

#define IN_F  1024
#define OUT_F 1024
#define NORD  13
#define BROWS 8192   // 4*2048

typedef __bf16 bf16x8 __attribute__((ext_vector_type(8)));
typedef float  f32x4  __attribute__((ext_vector_type(4)));
typedef unsigned short u16x8 __attribute__((ext_vector_type(8)));

__device__ __forceinline__ unsigned short f2bf(float f) {
  unsigned int u = __float_as_uint(f);
  unsigned int r = u + 0x7FFFu + ((u >> 16) & 1u);
  return (unsigned short)(r >> 16);
}
__device__ __forceinline__ float bf2f(unsigned short h) {
  return __uint_as_float(((unsigned int)h) << 16);
}
__device__ __forceinline__ float bfround(float f) { return bf2f(f2bf(f)); }

// global -> LDS async copy, 16B per lane.
__device__ __forceinline__ void gload_lds16(const void* g, void* l) {
  __builtin_amdgcn_global_load_lds(
      (__attribute__((address_space(1))) unsigned int*)(uintptr_t)g,
      (__attribute__((address_space(3))) unsigned int*)(unsigned int)(uintptr_t)l,
      16, 0, 0);
}

// ---------------- activation matrix: A[row][bb*1024+f] (bf16) ----------------
__global__ __launch_bounds__(256)
void act_kernel(const float* __restrict__ x, unsigned short* __restrict__ A,
                int b0, int nb, int Kp) {
  int t   = threadIdx.x;
  int row = blockIdx.x * 2 + (t >> 7);
  int f0  = (t & 127) * 8;
  const float* xr = x + (size_t)row * IN_F + f0;
  float xv[8];
  *(float4*)&xv[0] = *(const float4*)&xr[0];
  *(float4*)&xv[4] = *(const float4*)&xr[4];
  unsigned short* Ar = A + (size_t)row * Kp;
  int omax = b0 + nb - 1;
  if (b0 == 0) {
    // JAX bf16 silu: sigmoid rounded to bf16, then x*sigmoid rounded to bf16
    u16x8 sv;
#pragma unroll
    for (int i = 0; i < 8; i++) {
      float xc = bfround(xv[i]);
      float sg = bfround(1.0f / (1.0f + expf(-xc)));
      sv[i] = f2bf(xc * sg);
    }
    *(u16x8*)&Ar[f0] = sv;
  }
  float xs[8], tp[8], tc[8];
#pragma unroll
  for (int i = 0; i < 8; i++) { xs[i] = tanhf(xv[i]); tp[i] = 1.0f; tc[i] = xs[i]; }
  for (int o = 1; o <= omax; o++) {
    if (o >= b0) {
      int bb = o - b0;
      u16x8 sv;
#pragma unroll
      for (int i = 0; i < 8; i++) sv[i] = f2bf(tc[i]);
      *(u16x8*)&Ar[(size_t)bb * 1024 + f0] = sv;
    }
    {
#pragma clang fp contract(off)
#pragma unroll
      for (int i = 0; i < 8; i++) {
        float tm = 2.0f * xs[i] * tc[i];
        float tn = tm - tp[i];
        tp[i] = tc[i]; tc[i] = tn;
      }
    }
  }
}

// ---------------- weight transpose: Wt[n][bb*1024+f] = bf16(src_b[f][n]) ----------------
__global__ __launch_bounds__(256)
void wprep_kernel(const float* __restrict__ baseW, const float* __restrict__ poly,
                  unsigned short* __restrict__ Wt, int b0, int Kp) {
  __shared__ float tile[64][65];
  int bb = blockIdx.z;
  int g  = b0 + bb;
  const float* src = (g == 0) ? baseW : (poly + (size_t)g * (IN_F * OUT_F));
  int n0 = blockIdx.x * 64, f0 = blockIdx.y * 64;
  int tx = threadIdx.x, ty = threadIdx.y;  // 64 x 4
#pragma unroll
  for (int i = 0; i < 16; i++)
    tile[ty + i * 4][tx] = src[(size_t)(f0 + ty + i * 4) * OUT_F + n0 + tx];
  __syncthreads();
#pragma unroll
  for (int i = 0; i < 16; i++)
    Wt[(size_t)(n0 + ty + i * 4) * Kp + (size_t)bb * 1024 + f0 + tx] = f2bf(tile[tx][ty + i * 4]);
}

// ---------------- bias[n] = fp32 sum_f bf16(pw0[f][n]) (T0 == ones trick) ----------------
__global__ __launch_bounds__(256)
void bias_kernel(const float* __restrict__ pw0, float* __restrict__ bias) {
  int n = blockIdx.x * 256 + threadIdx.x;
  float s = 0.f;
  for (int f = 0; f < IN_F; f++) s += bf2f(f2bf(pw0[(size_t)f * OUT_F + n]));
  bias[n] = s;
}

// ---------------- GEMM with bf16 accumulation-chain emulation ----------------
// 128x128 tile, BK=64, order-block (1024-K) boundaries round: s = bf16(s + bf16(P_k)).
__global__ __launch_bounds__(256, 2)
void gemm_kernel(const unsigned short* __restrict__ A, const unsigned short* __restrict__ Wt,
                 float* __restrict__ outAcc, const float* __restrict__ bias,
                 int Kp, int isFirst) {
  __shared__ unsigned short sA[128 * 64];
  __shared__ unsigned short sB[128 * 64];
  int t    = threadIdx.x;
  int n0   = blockIdx.x * 128;
  int m0   = blockIdx.y * 128;
  int wave = t >> 6, lane = t & 63;
  int lr   = lane & 15, quad = lane >> 4;
  int wm   = (wave & 1) * 64, wn = (wave >> 1) * 64;

  int rs = t >> 3;
  int jg = (t & 7) ^ (rs & 7);
  const unsigned short* aSrc = A  + (size_t)(m0 + rs) * Kp + jg * 8;
  const unsigned short* bSrc = Wt + (size_t)(n0 + rs) * Kp + jg * 8;
  char* sAc = (char*)sA;
  char* sBc = (char*)sB;
  int ldsOff = t * 16;

  int aOff[4][2], bOff[4][2];
#pragma unroll
  for (int mi = 0; mi < 4; mi++) {
    int row = wm + mi * 16 + lr;
#pragma unroll
    for (int ks = 0; ks < 2; ks++) {
      int j = ks * 4 + quad;
      aOff[mi][ks] = row * 128 + ((j ^ (row & 7)) * 16);
    }
  }
#pragma unroll
  for (int ni = 0; ni < 4; ni++) {
    int row = wn + ni * 16 + lr;
#pragma unroll
    for (int ks = 0; ks < 2; ks++) {
      int j = ks * 4 + quad;
      bOff[ni][ks] = row * 128 + ((j ^ (row & 7)) * 16);
    }
  }

  // running bf16-valued sum s, and per-block fp32 MFMA accumulator acc
  f32x4 s[4][4];
  float bsr[4];
  if (isFirst) {
#pragma unroll
    for (int ni = 0; ni < 4; ni++) bsr[ni] = bfround(bias[n0 + wn + ni * 16 + lr]);
  } else {
#pragma unroll
    for (int ni = 0; ni < 4; ni++) {
      int gn = n0 + wn + ni * 16 + lr;
#pragma unroll
      for (int mi = 0; mi < 4; mi++) {
        int gmBase = m0 + wm + mi * 16 + quad * 4;
#pragma unroll
        for (int r = 0; r < 4; r++)
          s[mi][ni][r] = outAcc[(size_t)(gmBase + r) * OUT_F + gn];
      }
    }
  }

  int nBlk = Kp >> 10;
  for (int blk = 0; blk < nBlk; blk++) {
    f32x4 acc[4][4];
#pragma unroll
    for (int mi = 0; mi < 4; mi++)
#pragma unroll
      for (int ni = 0; ni < 4; ni++)
        acc[mi][ni] = (f32x4){0.f, 0.f, 0.f, 0.f};

    for (int kt = 0; kt < 16; kt++) {
      __syncthreads();
      const unsigned short* aP = aSrc + blk * 1024 + kt * 64;
      const unsigned short* bP = bSrc + blk * 1024 + kt * 64;
#pragma unroll
      for (int rd = 0; rd < 4; rd++)
        gload_lds16(aP + (size_t)rd * 32 * Kp, sAc + ldsOff + rd * 4096);
#pragma unroll
      for (int rd = 0; rd < 4; rd++)
        gload_lds16(bP + (size_t)rd * 32 * Kp, sBc + ldsOff + rd * 4096);
      __syncthreads();
#pragma unroll
      for (int ks = 0; ks < 2; ks++) {
        bf16x8 af[4], bfr[4];
#pragma unroll
        for (int mi = 0; mi < 4; mi++) af[mi] = *(const bf16x8*)(sAc + aOff[mi][ks]);
#pragma unroll
        for (int ni = 0; ni < 4; ni++) bfr[ni] = *(const bf16x8*)(sBc + bOff[ni][ks]);
#pragma unroll
        for (int mi = 0; mi < 4; mi++)
#pragma unroll
          for (int ni = 0; ni < 4; ni++)
            acc[mi][ni] = __builtin_amdgcn_mfma_f32_16x16x32_bf16(af[mi], bfr[ni], acc[mi][ni], 0, 0, 0);
      }
    }

    // bf16 chain update at the order-block boundary (matches ref rounding)
    bool firstBlk = (isFirst && blk == 0);
    if (firstBlk) {
#pragma unroll
      for (int mi = 0; mi < 4; mi++)
#pragma unroll
        for (int ni = 0; ni < 4; ni++)
#pragma unroll
          for (int r = 0; r < 4; r++) {
            float p = bfround(acc[mi][ni][r]);          // out = bf16 matmul result
            s[mi][ni][r] = bfround(p + bsr[ni]);        // out = bf16(out + bf16(bias))
          }
    } else {
#pragma unroll
      for (int mi = 0; mi < 4; mi++)
#pragma unroll
        for (int ni = 0; ni < 4; ni++)
#pragma unroll
          for (int r = 0; r < 4; r++)
            s[mi][ni][r] = bfround(s[mi][ni][r] + bfround(acc[mi][ni][r]));
    }
  }

  // store running sum (bf16-valued fp32, exact)
#pragma unroll
  for (int ni = 0; ni < 4; ni++) {
    int gn = n0 + wn + ni * 16 + lr;
#pragma unroll
    for (int mi = 0; mi < 4; mi++) {
      int gmBase = m0 + wm + mi * 16 + quad * 4;
#pragma unroll
      for (int r = 0; r < 4; r++)
        outAcc[(size_t)(gmBase + r) * OUT_F + gn] = s[mi][ni][r];
    }
  }
}

// ---------------- RMSNorm on bf16-valued outAcc ----------------
__global__ __launch_bounds__(256)
void rms_kernel(const float* __restrict__ outAcc, const float* __restrict__ scale,
                float* __restrict__ out) {
  int row = blockIdx.x;
  int t   = threadIdx.x;
  const float* src = outAcc + (size_t)row * OUT_F;
  float4 vv = *(const float4*)&src[t * 4];
  float v[4] = {vv.x, vv.y, vv.z, vv.w};
  float s = v[0]*v[0] + v[1]*v[1] + v[2]*v[2] + v[3]*v[3];
#pragma unroll
  for (int off = 32; off > 0; off >>= 1) s += __shfl_down(s, off, 64);
  __shared__ float red[4];
  if ((t & 63) == 0) red[t >> 6] = s;
  __syncthreads();
  float tot = red[0] + red[1] + red[2] + red[3];
  float sc = 1.0f / sqrtf(tot * (1.0f / OUT_F) + 1e-6f);
  float4 so = *(const float4*)&scale[t * 4];
  float4 o;
  o.x = v[0] * sc * so.x; o.y = v[1] * sc * so.y;
  o.z = v[2] * sc * so.z; o.w = v[3] * sc * so.w;
  *(float4*)&out[(size_t)row * OUT_F + t * 4] = o;
}

extern "C" void kernel_launch(void* const* d_in, const int* in_sizes, int n_in,
                              void* d_out, int out_size, void* d_ws, size_t ws_size,
                              hipStream_t stream) {
  const float* x     = (const float*)d_in[0];
  const float* baseW = (const float*)d_in[1];
  const float* poly  = (const float*)d_in[2];
  const float* scale = (const float*)d_in[3];
  float* out = (float*)d_out;

  char*  ws     = (char*)d_ws;
  float* outAcc = (float*)ws;                         // 8192*1024*4 = 33554432 B
  float* bias   = (float*)(ws + 33554432);            // 4096 B
  size_t fixed  = 33554432 + 4096;

  int CHB = 1;
  for (int c = NORD; c >= 1; c--) {
    size_t need = fixed + (size_t)c * 1024 * OUT_F * 2
                + (size_t)BROWS * c * 1024 * 2;
    if (need <= ws_size) { CHB = c; break; }
  }
  unsigned short* Wt = (unsigned short*)(ws + fixed);
  unsigned short* Ap = (unsigned short*)(ws + fixed + (size_t)CHB * 1024 * OUT_F * 2);

  bias_kernel<<<4, 256, 0, stream>>>(poly, bias);

  for (int b0 = 0; b0 < NORD; b0 += CHB) {
    int nb = (CHB < NORD - b0) ? CHB : (NORD - b0);
    int Kp = nb * 1024;
    act_kernel<<<BROWS / 2, 256, 0, stream>>>(x, Ap, b0, nb, Kp);
    wprep_kernel<<<dim3(16, 16, nb), dim3(64, 4), 0, stream>>>(baseW, poly, Wt, b0, Kp);
    gemm_kernel<<<dim3(8, BROWS / 128), 256, 0, stream>>>(Ap, Wt, outAcc, bias, Kp, (b0 == 0) ? 1 : 0);
  }
  rms_kernel<<<BROWS, 256, 0, stream>>>(outAcc, scale, out);
}

// Round 3
// 452.760 us; speedup vs baseline: 1.2321x; 1.2321x over previous
//
#include <hip/hip_runtime.h>
#include <cstdint>

#define IN_F  1024
#define OUT_F 1024
#define NORD  13
#define BROWS 8192   // 4*2048

typedef __bf16 bf16x8 __attribute__((ext_vector_type(8)));
typedef float  f32x4  __attribute__((ext_vector_type(4)));
typedef unsigned short u16x8 __attribute__((ext_vector_type(8)));
typedef unsigned short u16x4 __attribute__((ext_vector_type(4)));

__device__ __forceinline__ unsigned short f2bf(float f) {
  unsigned int u = __float_as_uint(f);
  unsigned int r = u + 0x7FFFu + ((u >> 16) & 1u);
  return (unsigned short)(r >> 16);
}
__device__ __forceinline__ float bf2f(unsigned short h) {
  return __uint_as_float(((unsigned int)h) << 16);
}
__device__ __forceinline__ float bfround(float f) { return bf2f(f2bf(f)); }

// global -> LDS async copy, 16B per lane.
__device__ __forceinline__ void gload_lds16(const void* g, void* l) {
  __builtin_amdgcn_global_load_lds(
      (__attribute__((address_space(1))) unsigned int*)(uintptr_t)g,
      (__attribute__((address_space(3))) unsigned int*)(unsigned int)(uintptr_t)l,
      16, 0, 0);
}

// ---------------- activation matrix: A[row][bb*1024+f] (bf16) ----------------
__global__ __launch_bounds__(256)
void act_kernel(const float* __restrict__ x, unsigned short* __restrict__ A,
                int b0, int nb, int Kp) {
  int t   = threadIdx.x;
  int row = blockIdx.x * 2 + (t >> 7);
  int f0  = (t & 127) * 8;
  const float* xr = x + (size_t)row * IN_F + f0;
  float xv[8];
  *(float4*)&xv[0] = *(const float4*)&xr[0];
  *(float4*)&xv[4] = *(const float4*)&xr[4];
  unsigned short* Ar = A + (size_t)row * Kp;
  int omax = b0 + nb - 1;
  if (b0 == 0) {
    // JAX bf16 silu: sigmoid rounded to bf16, then x*sigmoid rounded to bf16
    u16x8 sv;
#pragma unroll
    for (int i = 0; i < 8; i++) {
      float xc = bfround(xv[i]);
      float sg = bfround(1.0f / (1.0f + expf(-xc)));
      sv[i] = f2bf(xc * sg);
    }
    *(u16x8*)&Ar[f0] = sv;
  }
  float xs[8], tp[8], tc[8];
#pragma unroll
  for (int i = 0; i < 8; i++) { xs[i] = tanhf(xv[i]); tp[i] = 1.0f; tc[i] = xs[i]; }
  for (int o = 1; o <= omax; o++) {
    if (o >= b0) {
      int bb = o - b0;
      u16x8 sv;
#pragma unroll
      for (int i = 0; i < 8; i++) sv[i] = f2bf(tc[i]);
      *(u16x8*)&Ar[(size_t)bb * 1024 + f0] = sv;
    }
    {
#pragma clang fp contract(off)
#pragma unroll
      for (int i = 0; i < 8; i++) {
        float tm = 2.0f * xs[i] * tc[i];
        float tn = tm - tp[i];
        tp[i] = tc[i]; tc[i] = tn;
      }
    }
  }
}

// ---------------- weight transpose: Wt[n][bb*1024+f] = bf16(src_b[f][n]) ----------------
__global__ __launch_bounds__(256)
void wprep_kernel(const float* __restrict__ baseW, const float* __restrict__ poly,
                  unsigned short* __restrict__ Wt, int b0, int Kp) {
  __shared__ float tile[64][65];
  int bb = blockIdx.z;
  int g  = b0 + bb;
  const float* src = (g == 0) ? baseW : (poly + (size_t)g * (IN_F * OUT_F));
  int n0 = blockIdx.x * 64, f0 = blockIdx.y * 64;
  int tx = threadIdx.x, ty = threadIdx.y;  // 64 x 4
#pragma unroll
  for (int i = 0; i < 16; i++)
    tile[ty + i * 4][tx] = src[(size_t)(f0 + ty + i * 4) * OUT_F + n0 + tx];
  __syncthreads();
#pragma unroll
  for (int i = 0; i < 16; i++)
    Wt[(size_t)(n0 + ty + i * 4) * Kp + (size_t)bb * 1024 + f0 + tx] = f2bf(tile[tx][ty + i * 4]);
}

// ---------------- bias = colsum of bf16(pw0), two-phase parallel ----------------
__global__ __launch_bounds__(256)
void bias1_kernel(const float* __restrict__ pw0, float* __restrict__ partial) {
  int t  = threadIdx.x;
  int n  = blockIdx.x * 256 + t;
  int fc = blockIdx.y;            // 8 f-chunks of 128
  float s = 0.f;
  for (int f = fc * 128; f < fc * 128 + 128; f++)
    s += bf2f(f2bf(pw0[(size_t)f * OUT_F + n]));
  partial[(size_t)fc * OUT_F + n] = s;
}
__global__ __launch_bounds__(256)
void bias2_kernel(const float* __restrict__ partial, float* __restrict__ bias) {
  int n = blockIdx.x * 256 + threadIdx.x;
  float s = 0.f;
#pragma unroll
  for (int fc = 0; fc < 8; fc++) s += partial[(size_t)fc * OUT_F + n];
  bias[n] = s;
}

// ---------------- GEMM with bf16 accumulation-chain emulation ----------------
// 128x128 tile, BK=64. Grid (64 m-tiles, 8 n-tiles): linear id = m + 64*n, so
// id%8 == m%8 -> the 8 n-tiles sharing one A m-strip co-locate on one XCD (L2 reuse).
__global__ __launch_bounds__(256, 2)
void gemm_kernel(const unsigned short* __restrict__ A, const unsigned short* __restrict__ Wt,
                 unsigned short* __restrict__ outAcc, const float* __restrict__ bias,
                 int Kp, int isFirst) {
  __shared__ unsigned short sA[128 * 64];
  __shared__ unsigned short sB[128 * 64];
  int t    = threadIdx.x;
  int m0   = blockIdx.x * 128;   // 64 m-tiles (fast dim -> XCD round-robin on m)
  int n0   = blockIdx.y * 128;   // 8 n-tiles
  int wave = t >> 6, lane = t & 63;
  int lr   = lane & 15, quad = lane >> 4;
  int wm   = (wave & 1) * 64, wn = (wave >> 1) * 64;

  int rs = t >> 3;
  int jg = (t & 7) ^ (rs & 7);
  const unsigned short* aSrc = A  + (size_t)(m0 + rs) * Kp + jg * 8;
  const unsigned short* bSrc = Wt + (size_t)(n0 + rs) * Kp + jg * 8;
  char* sAc = (char*)sA;
  char* sBc = (char*)sB;
  int ldsOff = t * 16;

  int aOff[4][2], bOff[4][2];
#pragma unroll
  for (int mi = 0; mi < 4; mi++) {
    int row = wm + mi * 16 + lr;
#pragma unroll
    for (int ks = 0; ks < 2; ks++) {
      int j = ks * 4 + quad;
      aOff[mi][ks] = row * 128 + ((j ^ (row & 7)) * 16);
    }
  }
#pragma unroll
  for (int ni = 0; ni < 4; ni++) {
    int row = wn + ni * 16 + lr;
#pragma unroll
    for (int ks = 0; ks < 2; ks++) {
      int j = ks * 4 + quad;
      bOff[ni][ks] = row * 128 + ((j ^ (row & 7)) * 16);
    }
  }

  // running bf16-valued sum s, per-order-block fp32 MFMA accumulator acc
  f32x4 s[4][4];
  float bsr[4];
  if (isFirst) {
#pragma unroll
    for (int ni = 0; ni < 4; ni++) bsr[ni] = bfround(bias[n0 + wn + ni * 16 + lr]);
  } else {
#pragma unroll
    for (int ni = 0; ni < 4; ni++) {
      int gn = n0 + wn + ni * 16 + lr;
#pragma unroll
      for (int mi = 0; mi < 4; mi++) {
        int gmBase = m0 + wm + mi * 16 + quad * 4;
#pragma unroll
        for (int r = 0; r < 4; r++)
          s[mi][ni][r] = bf2f(outAcc[(size_t)(gmBase + r) * OUT_F + gn]);
      }
    }
  }

  int nBlk = Kp >> 10;
  for (int blk = 0; blk < nBlk; blk++) {
    f32x4 acc[4][4];
#pragma unroll
    for (int mi = 0; mi < 4; mi++)
#pragma unroll
      for (int ni = 0; ni < 4; ni++)
        acc[mi][ni] = (f32x4){0.f, 0.f, 0.f, 0.f};

    for (int kt = 0; kt < 16; kt++) {
      __syncthreads();
      const unsigned short* aP = aSrc + blk * 1024 + kt * 64;
      const unsigned short* bP = bSrc + blk * 1024 + kt * 64;
#pragma unroll
      for (int rd = 0; rd < 4; rd++)
        gload_lds16(aP + (size_t)rd * 32 * Kp, sAc + ldsOff + rd * 4096);
#pragma unroll
      for (int rd = 0; rd < 4; rd++)
        gload_lds16(bP + (size_t)rd * 32 * Kp, sBc + ldsOff + rd * 4096);
      __syncthreads();
#pragma unroll
      for (int ks = 0; ks < 2; ks++) {
        bf16x8 af[4], bfr[4];
#pragma unroll
        for (int mi = 0; mi < 4; mi++) af[mi] = *(const bf16x8*)(sAc + aOff[mi][ks]);
#pragma unroll
        for (int ni = 0; ni < 4; ni++) bfr[ni] = *(const bf16x8*)(sBc + bOff[ni][ks]);
#pragma unroll
        for (int mi = 0; mi < 4; mi++)
#pragma unroll
          for (int ni = 0; ni < 4; ni++)
            acc[mi][ni] = __builtin_amdgcn_mfma_f32_16x16x32_bf16(af[mi], bfr[ni], acc[mi][ni], 0, 0, 0);
      }
    }

    bool firstBlk = (isFirst && blk == 0);
    if (firstBlk) {
#pragma unroll
      for (int mi = 0; mi < 4; mi++)
#pragma unroll
        for (int ni = 0; ni < 4; ni++)
#pragma unroll
          for (int r = 0; r < 4; r++) {
            float p = bfround(acc[mi][ni][r]);          // out = bf16 matmul result
            s[mi][ni][r] = bfround(p + bsr[ni]);        // out = bf16(out + bf16(bias))
          }
    } else {
#pragma unroll
      for (int mi = 0; mi < 4; mi++)
#pragma unroll
        for (int ni = 0; ni < 4; ni++)
#pragma unroll
          for (int r = 0; r < 4; r++)
            s[mi][ni][r] = bfround(s[mi][ni][r] + bfround(acc[mi][ni][r]));
    }
  }

  // store running sum as bf16 (values are exactly bf16-representable)
#pragma unroll
  for (int ni = 0; ni < 4; ni++) {
    int gn = n0 + wn + ni * 16 + lr;
#pragma unroll
    for (int mi = 0; mi < 4; mi++) {
      int gmBase = m0 + wm + mi * 16 + quad * 4;
#pragma unroll
      for (int r = 0; r < 4; r++)
        outAcc[(size_t)(gmBase + r) * OUT_F + gn] = f2bf(s[mi][ni][r]);
    }
  }
}

// ---------------- RMSNorm on bf16 outAcc ----------------
__global__ __launch_bounds__(256)
void rms_kernel(const unsigned short* __restrict__ outAcc, const float* __restrict__ scale,
                float* __restrict__ out) {
  int row = blockIdx.x;
  int t   = threadIdx.x;
  const unsigned short* src = outAcc + (size_t)row * OUT_F;
  u16x4 hv = *(const u16x4*)&src[t * 4];
  float v[4];
#pragma unroll
  for (int i = 0; i < 4; i++) v[i] = bf2f(hv[i]);
  float s = v[0]*v[0] + v[1]*v[1] + v[2]*v[2] + v[3]*v[3];
#pragma unroll
  for (int off = 32; off > 0; off >>= 1) s += __shfl_down(s, off, 64);
  __shared__ float red[4];
  if ((t & 63) == 0) red[t >> 6] = s;
  __syncthreads();
  float tot = red[0] + red[1] + red[2] + red[3];
  float sc = 1.0f / sqrtf(tot * (1.0f / OUT_F) + 1e-6f);
  float4 so = *(const float4*)&scale[t * 4];
  float4 o;
  o.x = v[0] * sc * so.x; o.y = v[1] * sc * so.y;
  o.z = v[2] * sc * so.z; o.w = v[3] * sc * so.w;
  *(float4*)&out[(size_t)row * OUT_F + t * 4] = o;
}

extern "C" void kernel_launch(void* const* d_in, const int* in_sizes, int n_in,
                              void* d_out, int out_size, void* d_ws, size_t ws_size,
                              hipStream_t stream) {
  const float* x     = (const float*)d_in[0];
  const float* baseW = (const float*)d_in[1];
  const float* poly  = (const float*)d_in[2];
  const float* scale = (const float*)d_in[3];
  float* out = (float*)d_out;

  char* ws = (char*)d_ws;
  unsigned short* outAcc = (unsigned short*)ws;        // 8192*1024*2 = 16777216 B
  float* bias    = (float*)(ws + 16777216);            // 4096 B
  float* partial = (float*)(ws + 16777216 + 4096);     // 8*1024*4 = 32768 B
  size_t fixed   = 16777216 + 4096 + 32768;

  int CHB = 1;
  for (int c = NORD; c >= 1; c--) {
    size_t need = fixed + (size_t)c * 1024 * OUT_F * 2
                + (size_t)BROWS * c * 1024 * 2;
    if (need <= ws_size) { CHB = c; break; }
  }
  unsigned short* Wt = (unsigned short*)(ws + fixed);
  unsigned short* Ap = (unsigned short*)(ws + fixed + (size_t)CHB * 1024 * OUT_F * 2);

  bias1_kernel<<<dim3(4, 8), 256, 0, stream>>>(poly, partial);
  bias2_kernel<<<4, 256, 0, stream>>>(partial, bias);

  for (int b0 = 0; b0 < NORD; b0 += CHB) {
    int nb = (CHB < NORD - b0) ? CHB : (NORD - b0);
    int Kp = nb * 1024;
    act_kernel<<<BROWS / 2, 256, 0, stream>>>(x, Ap, b0, nb, Kp);
    wprep_kernel<<<dim3(16, 16, nb), dim3(64, 4), 0, stream>>>(baseW, poly, Wt, b0, Kp);
    gemm_kernel<<<dim3(BROWS / 128, 8), 256, 0, stream>>>(Ap, Wt, outAcc, bias, Kp, (b0 == 0) ? 1 : 0);
  }
  rms_kernel<<<BROWS, 256, 0, stream>>>(outAcc, scale, out);
}

// Round 4
// 405.474 us; speedup vs baseline: 1.3758x; 1.1166x over previous
//
#include <hip/hip_runtime.h>
#include <cstdint>

#define IN_F  1024
#define OUT_F 1024
#define NORD  13
#define BROWS 8192   // 4*2048

typedef __bf16 bf16x8 __attribute__((ext_vector_type(8)));
typedef float  f32x4  __attribute__((ext_vector_type(4)));
typedef unsigned short u16x8 __attribute__((ext_vector_type(8)));
typedef unsigned short u16x4 __attribute__((ext_vector_type(4)));

__device__ __forceinline__ unsigned short f2bf(float f) {
  unsigned int u = __float_as_uint(f);
  unsigned int r = u + 0x7FFFu + ((u >> 16) & 1u);
  return (unsigned short)(r >> 16);
}
__device__ __forceinline__ float bf2f(unsigned short h) {
  return __uint_as_float(((unsigned int)h) << 16);
}
__device__ __forceinline__ float bfround(float f) { return bf2f(f2bf(f)); }

// global -> LDS async copy, 16B per lane.
__device__ __forceinline__ void gload_lds16(const void* g, void* l) {
  __builtin_amdgcn_global_load_lds(
      (__attribute__((address_space(1))) unsigned int*)(uintptr_t)g,
      (__attribute__((address_space(3))) unsigned int*)(unsigned int)(uintptr_t)l,
      16, 0, 0);
}

// ---------------- activation matrix: A[row][bb*1024+f] (bf16) ----------------
__global__ __launch_bounds__(256)
void act_kernel(const float* __restrict__ x, unsigned short* __restrict__ A,
                int b0, int nb, int Kp) {
  int t   = threadIdx.x;
  int row = blockIdx.x * 2 + (t >> 7);
  int f0  = (t & 127) * 8;
  const float* xr = x + (size_t)row * IN_F + f0;
  float xv[8];
  *(float4*)&xv[0] = *(const float4*)&xr[0];
  *(float4*)&xv[4] = *(const float4*)&xr[4];
  unsigned short* Ar = A + (size_t)row * Kp;
  int omax = b0 + nb - 1;
  if (b0 == 0) {
    // JAX bf16 silu: sigmoid rounded to bf16, then x*sigmoid rounded to bf16
    u16x8 sv;
#pragma unroll
    for (int i = 0; i < 8; i++) {
      float xc = bfround(xv[i]);
      float sg = bfround(1.0f / (1.0f + expf(-xc)));
      sv[i] = f2bf(xc * sg);
    }
    *(u16x8*)&Ar[f0] = sv;
  }
  float xs[8], tp[8], tc[8];
#pragma unroll
  for (int i = 0; i < 8; i++) { xs[i] = tanhf(xv[i]); tp[i] = 1.0f; tc[i] = xs[i]; }
  for (int o = 1; o <= omax; o++) {
    if (o >= b0) {
      int bb = o - b0;
      u16x8 sv;
#pragma unroll
      for (int i = 0; i < 8; i++) sv[i] = f2bf(tc[i]);
      *(u16x8*)&Ar[(size_t)bb * 1024 + f0] = sv;
    }
    {
#pragma clang fp contract(off)
#pragma unroll
      for (int i = 0; i < 8; i++) {
        float tm = 2.0f * xs[i] * tc[i];
        float tn = tm - tp[i];
        tp[i] = tc[i]; tc[i] = tn;
      }
    }
  }
}

// ---------------- weight transpose: Wt[n][bb*1024+f] = bf16(src_b[f][n]) ----------------
__global__ __launch_bounds__(256)
void wprep_kernel(const float* __restrict__ baseW, const float* __restrict__ poly,
                  unsigned short* __restrict__ Wt, int b0, int Kp) {
  __shared__ float tile[64][65];
  int bb = blockIdx.z;
  int g  = b0 + bb;
  const float* src = (g == 0) ? baseW : (poly + (size_t)g * (IN_F * OUT_F));
  int n0 = blockIdx.x * 64, f0 = blockIdx.y * 64;
  int tx = threadIdx.x, ty = threadIdx.y;  // 64 x 4
#pragma unroll
  for (int i = 0; i < 16; i++)
    tile[ty + i * 4][tx] = src[(size_t)(f0 + ty + i * 4) * OUT_F + n0 + tx];
  __syncthreads();
#pragma unroll
  for (int i = 0; i < 16; i++)
    Wt[(size_t)(n0 + ty + i * 4) * Kp + (size_t)bb * 1024 + f0 + tx] = f2bf(tile[tx][ty + i * 4]);
}

// ---------------- bias = colsum of bf16(pw0), two-phase parallel ----------------
__global__ __launch_bounds__(256)
void bias1_kernel(const float* __restrict__ pw0, float* __restrict__ partial) {
  int t  = threadIdx.x;
  int n  = blockIdx.x * 256 + t;
  int fc = blockIdx.y;            // 8 f-chunks of 128
  float s = 0.f;
  for (int f = fc * 128; f < fc * 128 + 128; f++)
    s += bf2f(f2bf(pw0[(size_t)f * OUT_F + n]));
  partial[(size_t)fc * OUT_F + n] = s;
}
__global__ __launch_bounds__(256)
void bias2_kernel(const float* __restrict__ partial, float* __restrict__ bias) {
  int n = blockIdx.x * 256 + threadIdx.x;
  float s = 0.f;
#pragma unroll
  for (int fc = 0; fc < 8; fc++) s += partial[(size_t)fc * OUT_F + n];
  bias[n] = s;
}

// ---------------- GEMM: double-buffered LDS, 1 barrier/kt, prefetch-ahead ----------------
// 128x128 tile, BK=64. Grid (64 m-tiles, 8 n-tiles): id%8 == m%8 -> A-strip sharers
// co-locate on one XCD. bf16 accumulation-chain emulated at 1024-K boundaries.
__global__ __launch_bounds__(256, 2)
void gemm_kernel(const unsigned short* __restrict__ A, const unsigned short* __restrict__ Wt,
                 unsigned short* __restrict__ outAcc, const float* __restrict__ bias,
                 int Kp, int isFirst) {
  __shared__ unsigned short sA[2][128 * 64];  // 2 x 16 KB
  __shared__ unsigned short sB[2][128 * 64];  // 2 x 16 KB
  int t    = threadIdx.x;
  int m0   = blockIdx.x * 128;
  int n0   = blockIdx.y * 128;
  int wave = t >> 6, lane = t & 63;
  int lr   = lane & 15, quad = lane >> 4;
  int wm   = (wave & 1) * 64, wn = (wave >> 1) * 64;

  int rs = t >> 3;
  int jg = (t & 7) ^ (rs & 7);
  const unsigned short* aSrc = A  + (size_t)(m0 + rs) * Kp + jg * 8;
  const unsigned short* bSrc = Wt + (size_t)(n0 + rs) * Kp + jg * 8;
  char* sAc = (char*)sA;
  char* sBc = (char*)sB;
  int ldsOff = t * 16;

  int aOff[4][2], bOff[4][2];
#pragma unroll
  for (int mi = 0; mi < 4; mi++) {
    int row = wm + mi * 16 + lr;
#pragma unroll
    for (int ks = 0; ks < 2; ks++) {
      int j = ks * 4 + quad;
      aOff[mi][ks] = row * 128 + ((j ^ (row & 7)) * 16);
    }
  }
#pragma unroll
  for (int ni = 0; ni < 4; ni++) {
    int row = wn + ni * 16 + lr;
#pragma unroll
    for (int ks = 0; ks < 2; ks++) {
      int j = ks * 4 + quad;
      bOff[ni][ks] = row * 128 + ((j ^ (row & 7)) * 16);
    }
  }

  // running bf16-valued sum s
  f32x4 s[4][4];
  float bsr[4];
  if (isFirst) {
#pragma unroll
    for (int ni = 0; ni < 4; ni++) bsr[ni] = bfround(bias[n0 + wn + ni * 16 + lr]);
  } else {
#pragma unroll
    for (int ni = 0; ni < 4; ni++) {
      int gn = n0 + wn + ni * 16 + lr;
#pragma unroll
      for (int mi = 0; mi < 4; mi++) {
        int gmBase = m0 + wm + mi * 16 + quad * 4;
#pragma unroll
        for (int r = 0; r < 4; r++)
          s[mi][ni][r] = bf2f(outAcc[(size_t)(gmBase + r) * OUT_F + gn]);
      }
    }
  }

  int nKt  = Kp >> 6;    // 64-K steps
  int nBlk = Kp >> 10;   // 1024-K order blocks

  // stage tile gkt into buffer buf
  auto stage = [&](int gkt, int buf) {
    const unsigned short* aP = aSrc + gkt * 64;
    const unsigned short* bP = bSrc + gkt * 64;
    char* dA = sAc + buf * 16384 + ldsOff;
    char* dB = sBc + buf * 16384 + ldsOff;
#pragma unroll
    for (int rd = 0; rd < 4; rd++)
      gload_lds16(aP + (size_t)rd * 32 * Kp, dA + rd * 4096);
#pragma unroll
    for (int rd = 0; rd < 4; rd++)
      gload_lds16(bP + (size_t)rd * 32 * Kp, dB + rd * 4096);
  };

  stage(0, 0);  // prologue

  int gkt = 0;
  for (int blk = 0; blk < nBlk; blk++) {
    f32x4 acc[4][4];
#pragma unroll
    for (int mi = 0; mi < 4; mi++)
#pragma unroll
      for (int ni = 0; ni < 4; ni++)
        acc[mi][ni] = (f32x4){0.f, 0.f, 0.f, 0.f};

    for (int kt = 0; kt < 16; kt++, gkt++) {
      __syncthreads();               // drains vmcnt for tile gkt (issued 1 iter ago)
      int nxt = gkt + 1;
      if (nxt < nKt) stage(nxt, nxt & 1);   // prefetch: full compute phase to land
      int buf = gkt & 1;
      char* bA = sAc + buf * 16384;
      char* bB = sBc + buf * 16384;
#pragma unroll
      for (int ks = 0; ks < 2; ks++) {
        bf16x8 af[4], bfr[4];
#pragma unroll
        for (int mi = 0; mi < 4; mi++) af[mi] = *(const bf16x8*)(bA + aOff[mi][ks]);
#pragma unroll
        for (int ni = 0; ni < 4; ni++) bfr[ni] = *(const bf16x8*)(bB + bOff[ni][ks]);
#pragma unroll
        for (int mi = 0; mi < 4; mi++)
#pragma unroll
          for (int ni = 0; ni < 4; ni++)
            acc[mi][ni] = __builtin_amdgcn_mfma_f32_16x16x32_bf16(af[mi], bfr[ni], acc[mi][ni], 0, 0, 0);
      }
    }

    // bf16 chain update at the order-block boundary (matches ref rounding)
    bool firstBlk = (isFirst && blk == 0);
    if (firstBlk) {
#pragma unroll
      for (int mi = 0; mi < 4; mi++)
#pragma unroll
        for (int ni = 0; ni < 4; ni++)
#pragma unroll
          for (int r = 0; r < 4; r++) {
            float p = bfround(acc[mi][ni][r]);          // out = bf16 matmul result
            s[mi][ni][r] = bfround(p + bsr[ni]);        // out = bf16(out + bf16(bias))
          }
    } else {
#pragma unroll
      for (int mi = 0; mi < 4; mi++)
#pragma unroll
        for (int ni = 0; ni < 4; ni++)
#pragma unroll
          for (int r = 0; r < 4; r++)
            s[mi][ni][r] = bfround(s[mi][ni][r] + bfround(acc[mi][ni][r]));
    }
  }

  // store running sum as bf16 (values are exactly bf16-representable)
#pragma unroll
  for (int ni = 0; ni < 4; ni++) {
    int gn = n0 + wn + ni * 16 + lr;
#pragma unroll
    for (int mi = 0; mi < 4; mi++) {
      int gmBase = m0 + wm + mi * 16 + quad * 4;
#pragma unroll
      for (int r = 0; r < 4; r++)
        outAcc[(size_t)(gmBase + r) * OUT_F + gn] = f2bf(s[mi][ni][r]);
    }
  }
}

// ---------------- RMSNorm on bf16 outAcc ----------------
__global__ __launch_bounds__(256)
void rms_kernel(const unsigned short* __restrict__ outAcc, const float* __restrict__ scale,
                float* __restrict__ out) {
  int row = blockIdx.x;
  int t   = threadIdx.x;
  const unsigned short* src = outAcc + (size_t)row * OUT_F;
  u16x4 hv = *(const u16x4*)&src[t * 4];
  float v[4];
#pragma unroll
  for (int i = 0; i < 4; i++) v[i] = bf2f(hv[i]);
  float s = v[0]*v[0] + v[1]*v[1] + v[2]*v[2] + v[3]*v[3];
#pragma unroll
  for (int off = 32; off > 0; off >>= 1) s += __shfl_down(s, off, 64);
  __shared__ float red[4];
  if ((t & 63) == 0) red[t >> 6] = s;
  __syncthreads();
  float tot = red[0] + red[1] + red[2] + red[3];
  float sc = 1.0f / sqrtf(tot * (1.0f / OUT_F) + 1e-6f);
  float4 so = *(const float4*)&scale[t * 4];
  float4 o;
  o.x = v[0] * sc * so.x; o.y = v[1] * sc * so.y;
  o.z = v[2] * sc * so.z; o.w = v[3] * sc * so.w;
  *(float4*)&out[(size_t)row * OUT_F + t * 4] = o;
}

extern "C" void kernel_launch(void* const* d_in, const int* in_sizes, int n_in,
                              void* d_out, int out_size, void* d_ws, size_t ws_size,
                              hipStream_t stream) {
  const float* x     = (const float*)d_in[0];
  const float* baseW = (const float*)d_in[1];
  const float* poly  = (const float*)d_in[2];
  const float* scale = (const float*)d_in[3];
  float* out = (float*)d_out;

  char* ws = (char*)d_ws;
  unsigned short* outAcc = (unsigned short*)ws;        // 8192*1024*2 = 16777216 B
  float* bias    = (float*)(ws + 16777216);            // 4096 B
  float* partial = (float*)(ws + 16777216 + 4096);     // 8*1024*4 = 32768 B
  size_t fixed   = 16777216 + 4096 + 32768;

  int CHB = 1;
  for (int c = NORD; c >= 1; c--) {
    size_t need = fixed + (size_t)c * 1024 * OUT_F * 2
                + (size_t)BROWS * c * 1024 * 2;
    if (need <= ws_size) { CHB = c; break; }
  }
  unsigned short* Wt = (unsigned short*)(ws + fixed);
  unsigned short* Ap = (unsigned short*)(ws + fixed + (size_t)CHB * 1024 * OUT_F * 2);

  bias1_kernel<<<dim3(4, 8), 256, 0, stream>>>(poly, partial);
  bias2_kernel<<<4, 256, 0, stream>>>(partial, bias);

  for (int b0 = 0; b0 < NORD; b0 += CHB) {
    int nb = (CHB < NORD - b0) ? CHB : (NORD - b0);
    int Kp = nb * 1024;
    act_kernel<<<BROWS / 2, 256, 0, stream>>>(x, Ap, b0, nb, Kp);
    wprep_kernel<<<dim3(16, 16, nb), dim3(64, 4), 0, stream>>>(baseW, poly, Wt, b0, Kp);
    gemm_kernel<<<dim3(BROWS / 128, 8), 256, 0, stream>>>(Ap, Wt, outAcc, bias, Kp, (b0 == 0) ? 1 : 0);
  }
  rms_kernel<<<BROWS, 256, 0, stream>>>(outAcc, scale, out);
}